// Round 13
// baseline (82.528 us; speedup 1.0000x reference)
//
#include <hip/hip_runtime.h>

// r10 base (60.2 us, best) with ONE change: phase-3 tile layout is the
// (t,q)-exchange itself. Writer splits each retained quad into two float2s by
// t-plane (ds_write_b64, 2-way = free); reader gets its output quad as a single
// ds_read_b128 (2/bank/cycle = free). Everything else identical to r10.
//  phase 1: 16 chunks of 8 ch through XOR-swizzled slab, 2-deep reg prefetch,
//           9 sums S_d = sum_c p[x]*p[x+d], retain center quads in keep[16].
//  phase 2: inv = 1/sqrt(S_center) (+halo), sim = (1/9)*inv*sum_d inv[x+d]*S_d
//           (computed in both chalf lanes).
//  phase 3: out[b, c&1, h, w, c>>1] = keep * sim via T[128][33] exchange tile.

__device__ __forceinline__ float dot4acc(float4 a, float4 b, float acc) {
    acc = fmaf(a.x, b.x, acc);
    acc = fmaf(a.y, b.y, acc);
    acc = fmaf(a.z, b.z, acc);
    acc = fmaf(a.w, b.w, acc);
    return acc;
}

__global__ __launch_bounds__(256) void bcim_fused(const float* __restrict__ p,
                                                  float* __restrict__ out) {
    __shared__ float shbuf[4224];   // phase1: slab [6][64 quads][4] (1536 f); phase3: T[128][33]
    __shared__ float invL[192];

    const int tid = threadIdx.x;
    const int b  = blockIdx.x >> 3;
    const int r0 = (blockIdx.x & 7) << 2;
    const float* __restrict__ pb = p + (size_t)b * 131072;
    float* slab = shbuf;

    // ---- loader mapping (v3-verified) ----
    const int l_wq = tid & 7;
    const int l_c  = (tid >> 3) & 7;
    const int l_r  = tid >> 6;
    const int g0r  = r0 - 1 + l_r;
    const int g1r  = r0 + 3 + l_r;
    const bool in0 = ((unsigned)g0r < 32u);
    const bool in1 = (tid < 128) && ((unsigned)g1r < 32u);
    int wOff[4];
    {
        const int chh = l_c >> 2;
        const int ci  = l_c & 3;
        #pragma unroll
        for (int j = 0; j < 4; ++j) {
            const int u = ((l_wq << 3) + (j << 1) + chh) ^ l_wq;
            wOff[j] = l_r * 256 + u * 4 + ci;
        }
    }
    const int gOff0 = l_c * 1024 + g0r * 32 + l_wq * 4;
    const int gOff1 = l_c * 1024 + g1r * 32 + l_wq * 4;

    // ---- stencil mapping (v3-verified) ----
    const int chalf = tid & 1;
    const int pos   = tid >> 1;
    const int h     = pos >> 5;
    const int w     = pos & 31;
    const int wm    = (w > 0) ? w - 1 : 0;
    const int wp    = (w < 31) ? w + 1 : 31;
    const int uc    = (w  * 2 + chalf) ^ (w  >> 2);
    const int um    = (wm * 2 + chalf) ^ (wm >> 2);
    const int up    = (wp * 2 + chalf) ^ (wp >> 2);

    // 2-deep prefetch (A = even chunks, B = odd chunks)
    float4 A0 = make_float4(0.f,0.f,0.f,0.f), A1 = A0, B0 = A0, B1 = A0;
    if (in0) A0 = *(const float4*)(pb + gOff0);
    if (in1) A1 = *(const float4*)(pb + gOff1);
    if (in0) B0 = *(const float4*)(pb + 8192 + gOff0);
    if (in1) B1 = *(const float4*)(pb + 8192 + gOff1);

    float s0=0.f,s1=0.f,s2=0.f,s3=0.f,s4=0.f,s5=0.f,s6=0.f,s7=0.f,s8=0.f,hn=0.f;
    float4 keep[16];

    #define STEP(R0, R1, NEXTC, CUR) {                                              \
        slab[wOff[0]] = R0.x; slab[wOff[1]] = R0.y;                                 \
        slab[wOff[2]] = R0.z; slab[wOff[3]] = R0.w;                                 \
        if (tid < 128) {                                                            \
            slab[wOff[0] + 1024] = R1.x; slab[wOff[1] + 1024] = R1.y;               \
            slab[wOff[2] + 1024] = R1.z; slab[wOff[3] + 1024] = R1.w;               \
        }                                                                           \
        __syncthreads();                                                            \
        if ((NEXTC) < 16) {                                                         \
            if (in0) R0 = *(const float4*)(pb + (NEXTC) * 8192 + gOff0);            \
            if (in1) R1 = *(const float4*)(pb + (NEXTC) * 8192 + gOff1);            \
        }                                                                           \
        {                                                                           \
            const float4* sp = (const float4*)slab;                                 \
            const float4 ctr = sp[(h + 1) * 64 + uc];                               \
            keep[CUR] = ctr;                                                        \
            float4 n0 = sp[h * 64 + um];                                            \
            float4 n1 = sp[h * 64 + uc];                                            \
            float4 n2 = sp[h * 64 + up];                                            \
            s0 = dot4acc(ctr, n0, s0);                                              \
            s1 = dot4acc(ctr, n1, s1);                                              \
            s2 = dot4acc(ctr, n2, s2);                                              \
            if (h == 0) hn = dot4acc(n1, n1, hn);                                   \
            n0 = sp[(h + 2) * 64 + um];                                             \
            n1 = sp[(h + 2) * 64 + uc];                                             \
            n2 = sp[(h + 2) * 64 + up];                                             \
            s6 = dot4acc(ctr, n0, s6);                                              \
            s7 = dot4acc(ctr, n1, s7);                                              \
            s8 = dot4acc(ctr, n2, s8);                                              \
            if (h == 3) hn = dot4acc(n1, n1, hn);                                   \
            n0 = sp[(h + 1) * 64 + um];                                             \
            n2 = sp[(h + 1) * 64 + up];                                             \
            s3 = dot4acc(ctr, n0, s3);                                              \
            s4 = dot4acc(ctr, ctr, s4);                                             \
            s5 = dot4acc(ctr, n2, s5);                                              \
        }                                                                           \
        __syncthreads(); }

    #pragma unroll
    for (int ch = 0; ch < 16; ch += 2) {
        STEP(A0, A1, ch + 2, ch)
        STEP(B0, B1, ch + 3, ch + 1)
    }
    #undef STEP

    // pair-reduce channel halves (lanes 2k <-> 2k+1): both lanes get full sums
    s0 += __shfl_xor(s0, 1); s1 += __shfl_xor(s1, 1); s2 += __shfl_xor(s2, 1);
    s3 += __shfl_xor(s3, 1); s4 += __shfl_xor(s4, 1); s5 += __shfl_xor(s5, 1);
    s6 += __shfl_xor(s6, 1); s7 += __shfl_xor(s7, 1); s8 += __shfl_xor(s8, 1);
    hn += __shfl_xor(hn, 1);

    if (chalf == 0) {
        invL[(h + 1) * 32 + w] = (s4 > 0.f) ? (1.0f / sqrtf(s4)) : 0.f;
        if (h == 0) invL[w]       = (hn > 0.f) ? (1.0f / sqrtf(hn)) : 0.f;
        if (h == 3) invL[160 + w] = (hn > 0.f) ? (1.0f / sqrtf(hn)) : 0.f;
    }
    __syncthreads();

    float simreg;
    {
        const float mL = (w > 0)  ? 1.f : 0.f;
        const float mR = (w < 31) ? 1.f : 0.f;
        const float* iT = invL + h * 32;
        const float* iM = iT + 32;
        const float* iB = iM + 32;
        float acc;
        acc = s0 * (iT[wm] * mL);
        acc = fmaf(s1, iT[w],       acc);
        acc = fmaf(s2, iT[wp] * mR, acc);
        acc = fmaf(s3, iM[wm] * mL, acc);
        acc = fmaf(s4, iM[w],       acc);
        acc = fmaf(s5, iM[wp] * mR, acc);
        acc = fmaf(s6, iB[wm] * mL, acc);
        acc = fmaf(s7, iB[w],       acc);
        acc = fmaf(s8, iB[wp] * mR, acc);
        simreg = acc * iM[w] * (1.0f / 9.0f);
    }
    __syncthreads();   // all waves past slab use before tile overwrite

    // ---- phase 3: exchange tile T[128 pos][33] ----
    // writer lane (pos, chalf), chunk ch = cb*4 + ch':
    //   c = ch*8 + chalf*4 + j  ->  t = j&1,  q_local = ch'*4 + chalf*2 + (j>>1)
    //   t=0 gets (kk.x, kk.z), t=1 gets (kk.y, kk.w)  [float2 = ds_write_b64]
    // reader: one ds_read_b128 at T[pp*33 + t*16 + qf*4].
    float* T = shbuf;
    #pragma unroll
    for (int cb = 0; cb < 4; ++cb) {
        #pragma unroll
        for (int m = 0; m < 4; ++m) {
            float4 kk = keep[cb * 4 + m];
            kk.x *= simreg; kk.y *= simreg; kk.z *= simreg; kk.w *= simreg;
            const int qbase = pos * 33 + m * 4 + chalf * 2;
            *(float2*)&T[qbase]      = make_float2(kk.x, kk.z);   // t = 0
            *(float2*)&T[qbase + 16] = make_float2(kk.y, kk.w);   // t = 1
        }
        __syncthreads();
        #pragma unroll
        for (int stp = 0; stp < 4; ++stp) {
            const int flat = stp * 256 + tid;
            const int qf = flat & 3;
            const int t  = (flat >> 2) & 1;
            const int pp = flat >> 3;
            const int hh = pp >> 5;
            const int ww = pp & 31;
            const float4 o = *(const float4*)&T[pp * 33 + t * 16 + qf * 4];
            *(float4*)(out + (size_t)b * 131072 + (size_t)t * 65536 +
                       (size_t)(r0 + hh) * 2048 + ww * 64 + cb * 16 + qf * 4) = o;
        }
        __syncthreads();
    }
}

extern "C" void kernel_launch(void* const* d_in, const int* in_sizes, int n_in,
                              void* d_out, int out_size, void* d_ws, size_t ws_size,
                              hipStream_t stream) {
    const float* p = (const float*)d_in[0];
    float* out = (float*)d_out;
    bcim_fused<<<dim3(2048), dim3(256), 0, stream>>>(p, out);
    (void)in_sizes; (void)n_in; (void)out_size; (void)d_ws; (void)ws_size;
}

// Round 14
// 59.646 us; speedup vs baseline: 1.3836x; 1.3836x over previous
//
#include <hip/hip_runtime.h>

// r10 base (60.2 us best) + ONE fix: phase-3 exchange tile with ALIGNED stride-36
// layout (r13's stride 33 broke 8/16B alignment -> scalarized LDS ops).
//  phase 1: 16 chunks of 8 ch through XOR-swizzled slab, 2-deep reg prefetch,
//           9 sums S_d = sum_c p[x]*p[x+d], retain center quads in keep[16].
//  phase 2: inv = 1/sqrt(S_center) (+halo), sim = (1/9)*inv*sum_d inv[x+d]*S_d
//           (computed in both chalf lanes).
//  phase 3: writer splits each quad into two ALIGNED float2 by t-plane:
//           T[pos][t*16 + qlocal], qlocal = m*4 + chalf*2 + {0,1}; reader takes
//           its output quad as one aligned ds_read_b128 at T[pp*36 + t*16 + qf*4].

__device__ __forceinline__ float dot4acc(float4 a, float4 b, float acc) {
    acc = fmaf(a.x, b.x, acc);
    acc = fmaf(a.y, b.y, acc);
    acc = fmaf(a.z, b.z, acc);
    acc = fmaf(a.w, b.w, acc);
    return acc;
}

__global__ __launch_bounds__(256) void bcim_fused(const float* __restrict__ p,
                                                  float* __restrict__ out) {
    __shared__ float shbuf[4608];   // phase1: slab [6][64 quads][4] (1536 f); phase3: T[128][36]
    __shared__ float invL[192];

    const int tid = threadIdx.x;
    const int b  = blockIdx.x >> 3;
    const int r0 = (blockIdx.x & 7) << 2;
    const float* __restrict__ pb = p + (size_t)b * 131072;
    float* slab = shbuf;

    // ---- loader mapping (v3-verified) ----
    const int l_wq = tid & 7;
    const int l_c  = (tid >> 3) & 7;
    const int l_r  = tid >> 6;
    const int g0r  = r0 - 1 + l_r;
    const int g1r  = r0 + 3 + l_r;
    const bool in0 = ((unsigned)g0r < 32u);
    const bool in1 = (tid < 128) && ((unsigned)g1r < 32u);
    int wOff[4];
    {
        const int chh = l_c >> 2;
        const int ci  = l_c & 3;
        #pragma unroll
        for (int j = 0; j < 4; ++j) {
            const int u = ((l_wq << 3) + (j << 1) + chh) ^ l_wq;
            wOff[j] = l_r * 256 + u * 4 + ci;
        }
    }
    const int gOff0 = l_c * 1024 + g0r * 32 + l_wq * 4;
    const int gOff1 = l_c * 1024 + g1r * 32 + l_wq * 4;

    // ---- stencil mapping (v3-verified) ----
    const int chalf = tid & 1;
    const int pos   = tid >> 1;
    const int h     = pos >> 5;
    const int w     = pos & 31;
    const int wm    = (w > 0) ? w - 1 : 0;
    const int wp    = (w < 31) ? w + 1 : 31;
    const int uc    = (w  * 2 + chalf) ^ (w  >> 2);
    const int um    = (wm * 2 + chalf) ^ (wm >> 2);
    const int up    = (wp * 2 + chalf) ^ (wp >> 2);

    // 2-deep prefetch (A = even chunks, B = odd chunks)
    float4 A0 = make_float4(0.f,0.f,0.f,0.f), A1 = A0, B0 = A0, B1 = A0;
    if (in0) A0 = *(const float4*)(pb + gOff0);
    if (in1) A1 = *(const float4*)(pb + gOff1);
    if (in0) B0 = *(const float4*)(pb + 8192 + gOff0);
    if (in1) B1 = *(const float4*)(pb + 8192 + gOff1);

    float s0=0.f,s1=0.f,s2=0.f,s3=0.f,s4=0.f,s5=0.f,s6=0.f,s7=0.f,s8=0.f,hn=0.f;
    float4 keep[16];

    #define STEP(R0, R1, NEXTC, CUR) {                                              \
        slab[wOff[0]] = R0.x; slab[wOff[1]] = R0.y;                                 \
        slab[wOff[2]] = R0.z; slab[wOff[3]] = R0.w;                                 \
        if (tid < 128) {                                                            \
            slab[wOff[0] + 1024] = R1.x; slab[wOff[1] + 1024] = R1.y;               \
            slab[wOff[2] + 1024] = R1.z; slab[wOff[3] + 1024] = R1.w;               \
        }                                                                           \
        __syncthreads();                                                            \
        if ((NEXTC) < 16) {                                                         \
            if (in0) R0 = *(const float4*)(pb + (NEXTC) * 8192 + gOff0);            \
            if (in1) R1 = *(const float4*)(pb + (NEXTC) * 8192 + gOff1);            \
        }                                                                           \
        {                                                                           \
            const float4* sp = (const float4*)slab;                                 \
            const float4 ctr = sp[(h + 1) * 64 + uc];                               \
            keep[CUR] = ctr;                                                        \
            float4 n0 = sp[h * 64 + um];                                            \
            float4 n1 = sp[h * 64 + uc];                                            \
            float4 n2 = sp[h * 64 + up];                                            \
            s0 = dot4acc(ctr, n0, s0);                                              \
            s1 = dot4acc(ctr, n1, s1);                                              \
            s2 = dot4acc(ctr, n2, s2);                                              \
            if (h == 0) hn = dot4acc(n1, n1, hn);                                   \
            n0 = sp[(h + 2) * 64 + um];                                             \
            n1 = sp[(h + 2) * 64 + uc];                                             \
            n2 = sp[(h + 2) * 64 + up];                                             \
            s6 = dot4acc(ctr, n0, s6);                                              \
            s7 = dot4acc(ctr, n1, s7);                                              \
            s8 = dot4acc(ctr, n2, s8);                                              \
            if (h == 3) hn = dot4acc(n1, n1, hn);                                   \
            n0 = sp[(h + 1) * 64 + um];                                             \
            n2 = sp[(h + 1) * 64 + up];                                             \
            s3 = dot4acc(ctr, n0, s3);                                              \
            s4 = dot4acc(ctr, ctr, s4);                                             \
            s5 = dot4acc(ctr, n2, s5);                                              \
        }                                                                           \
        __syncthreads(); }

    #pragma unroll
    for (int ch = 0; ch < 16; ch += 2) {
        STEP(A0, A1, ch + 2, ch)
        STEP(B0, B1, ch + 3, ch + 1)
    }
    #undef STEP

    // pair-reduce channel halves (lanes 2k <-> 2k+1): both lanes get full sums
    s0 += __shfl_xor(s0, 1); s1 += __shfl_xor(s1, 1); s2 += __shfl_xor(s2, 1);
    s3 += __shfl_xor(s3, 1); s4 += __shfl_xor(s4, 1); s5 += __shfl_xor(s5, 1);
    s6 += __shfl_xor(s6, 1); s7 += __shfl_xor(s7, 1); s8 += __shfl_xor(s8, 1);
    hn += __shfl_xor(hn, 1);

    if (chalf == 0) {
        invL[(h + 1) * 32 + w] = (s4 > 0.f) ? (1.0f / sqrtf(s4)) : 0.f;
        if (h == 0) invL[w]       = (hn > 0.f) ? (1.0f / sqrtf(hn)) : 0.f;
        if (h == 3) invL[160 + w] = (hn > 0.f) ? (1.0f / sqrtf(hn)) : 0.f;
    }
    __syncthreads();

    float simreg;
    {
        const float mL = (w > 0)  ? 1.f : 0.f;
        const float mR = (w < 31) ? 1.f : 0.f;
        const float* iT = invL + h * 32;
        const float* iM = iT + 32;
        const float* iB = iM + 32;
        float acc;
        acc = s0 * (iT[wm] * mL);
        acc = fmaf(s1, iT[w],       acc);
        acc = fmaf(s2, iT[wp] * mR, acc);
        acc = fmaf(s3, iM[wm] * mL, acc);
        acc = fmaf(s4, iM[w],       acc);
        acc = fmaf(s5, iM[wp] * mR, acc);
        acc = fmaf(s6, iB[wm] * mL, acc);
        acc = fmaf(s7, iB[w],       acc);
        acc = fmaf(s8, iB[wp] * mR, acc);
        simreg = acc * iM[w] * (1.0f / 9.0f);
    }
    __syncthreads();   // all waves past slab use before tile overwrite

    // ---- phase 3: exchange tile T[128 pos][36], all accesses aligned ----
    // writer lane (pos, chalf), chunk ch = cb*4 + m:
    //   c = ch*8 + chalf*4 + j  ->  t = j&1,  qlocal = m*4 + chalf*2 + (j>>1)
    //   t=0 plane (row offset 0):  (kk.x, kk.z) ; t=1 plane (offset 16): (kk.y, kk.w)
    // reader: one ds_read_b128 at T[pp*36 + t*16 + qf*4].
    float* T = shbuf;
    #pragma unroll
    for (int cb = 0; cb < 4; ++cb) {
        #pragma unroll
        for (int m = 0; m < 4; ++m) {
            float4 kk = keep[cb * 4 + m];
            kk.x *= simreg; kk.y *= simreg; kk.z *= simreg; kk.w *= simreg;
            const int qbase = pos * 36 + m * 4 + chalf * 2;   // even -> 8B aligned
            *(float2*)&T[qbase]      = make_float2(kk.x, kk.z);   // t = 0
            *(float2*)&T[qbase + 16] = make_float2(kk.y, kk.w);   // t = 1
        }
        __syncthreads();
        #pragma unroll
        for (int stp = 0; stp < 4; ++stp) {
            const int flat = stp * 256 + tid;
            const int qf = flat & 3;
            const int t  = (flat >> 2) & 1;
            const int pp = flat >> 3;
            const int hh = pp >> 5;
            const int ww = pp & 31;
            const float4 o = *(const float4*)&T[pp * 36 + t * 16 + qf * 4];
            *(float4*)(out + (size_t)b * 131072 + (size_t)t * 65536 +
                       (size_t)(r0 + hh) * 2048 + ww * 64 + cb * 16 + qf * 4) = o;
        }
        __syncthreads();
    }
}

extern "C" void kernel_launch(void* const* d_in, const int* in_sizes, int n_in,
                              void* d_out, int out_size, void* d_ws, size_t ws_size,
                              hipStream_t stream) {
    const float* p = (const float*)d_in[0];
    float* out = (float*)d_out;
    bcim_fused<<<dim3(2048), dim3(256), 0, stream>>>(p, out);
    (void)in_sizes; (void)n_in; (void)out_size; (void)d_ws; (void)ws_size;
}